// Round 6
// baseline (1161.719 us; speedup 1.0000x reference)
//
#include <hip/hip_runtime.h>
#include <stdint.h>

// ---------------- problem constants ----------------
static constexpr int Hd   = 1024;     // H_DIM
static constexpr int BZn  = 256;      // batch
static constexpr int MTOT = 131072;   // 32 * 4096 keys
static constexpr int BM   = 64;       // key rows per block (main kernel)
static constexpr int NU   = 7;        // units

typedef float  f32x4  __attribute__((ext_vector_type(4)));
typedef short  bf16x8 __attribute__((ext_vector_type(8)));
typedef unsigned short u16;

__device__ __forceinline__ u16 f2bf(float f) {
    unsigned int u = __float_as_uint(f);
    unsigned int r = (u + 0x7FFFu + ((u >> 16) & 1u)) >> 16;  // RNE
    return (u16)r;
}
__device__ __forceinline__ float bf2f(u16 h) {
    return __uint_as_float(((unsigned int)h) << 16);
}

// ---------------- prep kernels ----------------

// Qrot[256][1024] = query @ R  (f32). 64 blocks x 4 rows.
__global__ void k_qrot(const float* __restrict__ query, const float* __restrict__ R,
                       float* __restrict__ Qrot) {
    __shared__ float qt[4][Hd];
    const int t = threadIdx.x;
    const int r0 = blockIdx.x * 4;
    for (int r = 0; r < 4; ++r)
        *(float4*)(&qt[r][t * 4]) = *(const float4*)(query + (long long)(r0 + r) * Hd + t * 4);
    __syncthreads();
    float acc[4][4] = {};
    for (int k = 0; k < Hd; ++k) {
        float4 rv = *(const float4*)(R + (long long)k * Hd + t * 4);
#pragma unroll
        for (int r = 0; r < 4; ++r) {
            float qv = qt[r][k];
            acc[r][0] += qv * rv.x; acc[r][1] += qv * rv.y;
            acc[r][2] += qv * rv.z; acc[r][3] += qv * rv.w;
        }
    }
    for (int r = 0; r < 4; ++r) {
        float4 o; o.x = acc[r][0]; o.y = acc[r][1]; o.z = acc[r][2]; o.w = acc[r][3];
        *(float4*)(Qrot + (long long)(r0 + r) * Hd + t * 4) = o;
    }
}

// Rpack: B-fragment layout for mfma_f32_16x16x32_bf16.
// frag id = (c0/16)*32 + (k0/32); lane l holds B[k0+(l>>4)*8+j][c0+(l&15)], j=0..7.
__global__ void k_rpack(const float* __restrict__ R, u16* __restrict__ Rpack) {
    const int gt = blockIdx.x * 256 + threadIdx.x;
    const int frag = gt >> 6, lam = gt & 63;
    const int cblk = frag >> 5, kblk = frag & 31;
    const int c  = cblk * 16 + (lam & 15);
    const int k0 = kblk * 32 + (lam >> 4) * 8;
    union { bf16x8 v; u16 u[8]; } p;
#pragma unroll
    for (int j = 0; j < 8; ++j) p.u[j] = f2bf(R[(long long)(k0 + j) * Hd + c]);
    *(bf16x8*)(Rpack + (long long)frag * 512 + lam * 8) = p.v;
}

// Qpack: A-fragment layout. frag id = (c0/32)*16 + (q0/16);
// lane l holds A[q0+(l&15)][c0+(l>>4)*8+j].
__global__ void k_qpack(const float* __restrict__ Qrot, u16* __restrict__ Qpack) {
    const int gt = blockIdx.x * 256 + threadIdx.x;
    const int frag = gt >> 6, lam = gt & 63;
    const int cblk = frag >> 4, qblk = frag & 15;
    const int q  = qblk * 16 + (lam & 15);
    const int c0 = cblk * 32 + (lam >> 4) * 8;
    union { bf16x8 v; u16 u[8]; } p;
#pragma unroll
    for (int j = 0; j < 8; ++j) p.u[j] = f2bf(Qrot[(long long)q * Hd + c0 + j]);
    *(bf16x8*)(Qpack + (long long)frag * 512 + lam * 8) = p.v;
}

// ---------------- fused main kernel (1024 threads = 16 waves, 4 waves/SIMD) ----------------
// LDS: keysA[131072] | Krot[32768] = 163840 B (exactly 160 KiB, 1 block/CU)
static constexpr int LDS_TOT = 163840;

// Krot addressing: [key][512B row]; 16B slot rotated by 2*key:
//   byte(key, col) = key*512 + ((((col>>3) + 2*key) & 31) << 4) + (col&7)*2
// read of 8 consecutive cols (col&7==0) is one aligned b128.

__global__ __launch_bounds__(1024, 4)
void k_main(const float* __restrict__ keys, const u16* __restrict__ Rp,
            const u16* __restrict__ Qp, unsigned long long* __restrict__ best) {
    extern __shared__ char smem[];
    char* keysA = smem;
    char* Krot  = smem + 131072;

    const int t   = threadIdx.x;
    const int lam = t & 63;
    const int w   = t >> 6;          // 16 waves
    const int l15 = lam & 15;
    const int lg  = lam >> 4;
    const int cs  = w >> 1;          // col-strip (32 cols per quarter)
    const int h   = w & 1;           // key half (32 keys)
    const int row0 = blockIdx.x * BM;

    // ---- stage this block's 64 key rows: f32 -> bf16, swizzled ----
    {
        const float* kb = keys + (long long)row0 * Hd;
#pragma unroll
        for (int i = 0; i < 8; ++i) {
            int e0 = i * 8192 + t * 8;
            float4 v0 = *(const float4*)(kb + e0);
            float4 v1 = *(const float4*)(kb + e0 + 4);
            int row = e0 >> 10, k = e0 & 1023;
            union { bf16x8 v; u16 u[8]; } p;
            p.u[0] = f2bf(v0.x); p.u[1] = f2bf(v0.y); p.u[2] = f2bf(v0.z); p.u[3] = f2bf(v0.w);
            p.u[4] = f2bf(v1.x); p.u[5] = f2bf(v1.y); p.u[6] = f2bf(v1.z); p.u[7] = f2bf(v1.w);
            int byte = (row * 2048 + k * 2) ^ ((row & 7) << 4);
            *(bf16x8*)(keysA + byte) = p.v;
        }
    }
    __syncthreads();

    const char* RpB = (const char*)Rp;
    const int arow  = h * 32 + l15;          // A rows this lane touches: + m*16
    const int aswz  = (l15 & 7) << 4;        // (row&7) == (l15&7) for both m

#pragma unroll 1
    for (int q = 0; q < 4; ++q) {
        // ==== rotation: wave owns cols q*256 + cs*32 + [0,32), keys h*32 + [0,32) ====
        const char* bb0 = RpB + (long long)((q * 16 + cs * 2 + 0) * 32) * 1024 + lam * 16;
        const char* bb1 = RpB + (long long)((q * 16 + cs * 2 + 1) * 32) * 1024 + lam * 16;

        f32x4 racc[2][2];
#pragma unroll
        for (int m = 0; m < 2; ++m) { racc[m][0] = (f32x4){0,0,0,0}; racc[m][1] = (f32x4){0,0,0,0}; }

        // depth-2 B prefetch ring
        bf16x8 nbA0 = *(const bf16x8*)(bb0);
        bf16x8 nbA1 = *(const bf16x8*)(bb1);
        bf16x8 nbB0 = *(const bf16x8*)(bb0 + 1024);
        bf16x8 nbB1 = *(const bf16x8*)(bb1 + 1024);

#pragma unroll 4
        for (int ks = 0; ks < 32; ++ks) {
            bf16x8 cb0 = nbA0, cb1 = nbA1;
            nbA0 = nbB0; nbA1 = nbB1;
            if (ks < 30) {
                nbB0 = *(const bf16x8*)(bb0 + (ks + 2) * 1024);
                nbB1 = *(const bf16x8*)(bb1 + (ks + 2) * 1024);
            }
#pragma unroll
            for (int m = 0; m < 2; ++m) {
                int abyte = (((arow + m * 16) * 2048) + (ks * 32 + lg * 8) * 2) ^ aswz;
                bf16x8 a = *(const bf16x8*)(keysA + abyte);
                racc[m][0] = __builtin_amdgcn_mfma_f32_16x16x32_bf16(a, cb0, racc[m][0], 0, 0, 0);
                racc[m][1] = __builtin_amdgcn_mfma_f32_16x16x32_bf16(a, cb1, racc[m][1], 0, 0, 0);
            }
        }

        __syncthreads();   // previous quarter's sims done reading Krot

        // ---- write Krot: key = h*32+m*16+lg*4+e, col = cs*32+n*16+l15 ----
#pragma unroll
        for (int m = 0; m < 2; ++m)
#pragma unroll
            for (int n = 0; n < 2; ++n) {
                int qcol = cs * 32 + n * 16 + l15;
#pragma unroll
                for (int e = 0; e < 4; ++e) {
                    int key = h * 32 + m * 16 + lg * 4 + e;
                    int byte = key * 512 + ((((qcol >> 3) + 2 * key) & 31) << 4) + (qcol & 7) * 2;
                    *(u16*)(Krot + byte) = f2bf(racc[m][n][e]);
                }
            }
        __syncthreads();   // Krot visible

        // ==== sims: wave owns queries cs*32 + [0,32), keys h*32 + [0,32) ====
        const int ubase = (q == 0) ? 0 : (q == 1) ? 1 : (q == 2) ? 2 : 4;
        const int fmask = (q < 2) ? 0x80 : (q == 2) ? 0x88 : 0xA8;

        f32x4 acc[2][2];
#pragma unroll
        for (int m = 0; m < 2; ++m) { acc[m][0] = (f32x4){0,0,0,0}; acc[m][1] = (f32x4){0,0,0,0}; }
        float nrm[2] = {0.f, 0.f};
        int u = ubase;

#pragma unroll
        for (int ks = 0; ks < 8; ++ks) {
            bf16x8 aq[2], bk[2];
            int cblk = q * 8 + ks;
#pragma unroll
            for (int m = 0; m < 2; ++m) {
                long long qoff = ((long long)(cblk * 16 + (cs * 2 + m)) * 64 + lam) * 8;
                aq[m] = *(const bf16x8*)(Qp + qoff);
            }
#pragma unroll
            for (int n = 0; n < 2; ++n) {
                int key = h * 32 + n * 16 + l15;
                int slot = ((ks * 4 + lg) + 2 * key) & 31;
                bk[n] = *(const bf16x8*)(Krot + key * 512 + (slot << 4));
            }
#pragma unroll
            for (int m = 0; m < 2; ++m)
#pragma unroll
                for (int n = 0; n < 2; ++n)
                    acc[m][n] = __builtin_amdgcn_mfma_f32_16x16x32_bf16(aq[m], bk[n], acc[m][n], 0, 0, 0);
            // per-key norm partials from the bf16 Krot values just read
#pragma unroll
            for (int n = 0; n < 2; ++n) {
                union { bf16x8 v; u16 s[8]; } ub; ub.v = bk[n];
#pragma unroll
                for (int j = 0; j < 8; ++j) { float f = bf2f(ub.s[j]); nrm[n] = fmaf(f, f, nrm[n]); }
            }

            if ((fmask >> ks) & 1) {
                // ---- flush unit u: norms across lg, scale, packed-u32 argmax, atomic ----
                float rn2[2];
#pragma unroll
                for (int n = 0; n < 2; ++n) {
                    float s = nrm[n];
                    s += __shfl_xor(s, 16);
                    s += __shfl_xor(s, 32);
                    rn2[n] = 1.0f / fmaxf(sqrtf(s), 1e-3f);
                    nrm[n] = 0.f;
                }
#pragma unroll
                for (int m = 0; m < 2; ++m) {
#pragma unroll
                    for (int e = 0; e < 4; ++e) {
                        float v0 = acc[m][0][e] * rn2[0];
                        float v1 = acc[m][1][e] * rn2[1];
                        float bv; int bi6;
                        if (v1 > v0) { bv = v1; bi6 = h * 32 + 16 + l15; }
                        else         { bv = v0; bi6 = h * 32 + l15; }
                        unsigned int ui = __float_as_uint(bv);
                        unsigned int mp = ui ^ (((int)ui < 0) ? 0xFFFFFFFFu : 0x80000000u);
                        unsigned int enc = (mp & 0xFFFFFFC0u) | (63u - (unsigned int)bi6);
#pragma unroll
                        for (int mask = 1; mask <= 8; mask <<= 1) {
                            unsigned int o = __shfl_xor(enc, mask);
                            enc = (o > enc) ? o : enc;
                        }
                        if (l15 == 0) {
                            int bi = 63 - (int)(enc & 63u);
                            unsigned int gl = (unsigned int)(row0 + bi);
                            unsigned long long e64 =
                                ((unsigned long long)(enc & 0xFFFFFFC0u) << 32) |
                                (unsigned long long)(0xFFFFFFFFu - gl);
                            int qq = cs * 32 + m * 16 + lg * 4 + e;
                            unsigned long long* addr = best + u * BZn + qq;
                            if (e64 > *addr) atomicMax(addr, e64);
                        }
                    }
#pragma unroll
                    for (int n = 0; n < 2; ++n) acc[m][n] = (f32x4){0,0,0,0};
                }
                ++u;
            }
        }
    }
}

// ---------------- finish: exact f32 cosine of the winners ----------------
__global__ void k_final(const float* __restrict__ keys, const float* __restrict__ R,
                        const float* __restrict__ Qrot,
                        const unsigned long long* __restrict__ best, float* __restrict__ out) {
    const int fid = blockIdx.x;
    const int u = fid >> 8, b = fid & 255;
    int off, d;
    if (u < 2)      { off = u * 256;            d = 256; }
    else if (u < 5) { off = 512 + (u - 2) * 128; d = 128; }
    else            { off = 896 + (u - 5) * 64;  d = 64;  }

    unsigned long long ent = best[fid];
    if (ent == 0ull) return;  // no winner -> zero vector -> cos = 0

    __shared__ float krow[Hd];
    __shared__ float red[12];
    const int t = threadIdx.x;
    unsigned int gl = 0xFFFFFFFFu - (unsigned int)(ent & 0xFFFFFFFFull);
    const float* kp = keys + (long long)gl * Hd;
    *(float4*)(&krow[t * 4]) = *(const float4*)(kp + t * 4);
    __syncthreads();

    float pn = 0.f, pq = 0.f, pk = 0.f;
    if (t < d) {
        float kr = 0.f;
        for (int k = 0; k < Hd; ++k) kr += krow[k] * R[(long long)k * Hd + off + t];
        float qv = Qrot[(long long)b * Hd + off + t];
        pn = qv * kr; pq = qv * qv; pk = kr * kr;
    }
    for (int mask = 1; mask <= 32; mask <<= 1) {
        pn += __shfl_xor(pn, mask); pq += __shfl_xor(pq, mask); pk += __shfl_xor(pk, mask);
    }
    if ((t & 63) == 0) { red[t >> 6] = pn; red[4 + (t >> 6)] = pq; red[8 + (t >> 6)] = pk; }
    __syncthreads();
    if (t == 0) {
        float nm = red[0] + red[1] + red[2] + red[3];
        float qq = red[4] + red[5] + red[6] + red[7];
        float kk = red[8] + red[9] + red[10] + red[11];
        float cosv = nm / (fmaxf(sqrtf(qq), 1e-8f) * fmaxf(sqrtf(kk), 1e-8f));
        atomicAdd(out, -cosv * (float)d / (256.0f * 1024.0f));
    }
}

// ---------------- launch ----------------
extern "C" void kernel_launch(void* const* d_in, const int* in_sizes, int n_in,
                              void* d_out, int out_size, void* d_ws, size_t ws_size,
                              hipStream_t stream) {
    (void)in_sizes; (void)n_in; (void)out_size; (void)ws_size;
    const float* query = (const float*)d_in[0];
    const float* keys  = (const float*)d_in[1];
    const float* R     = (const float*)d_in[2];
    float* out = (float*)d_out;
    char* ws = (char*)d_ws;

    unsigned long long* best = (unsigned long long*)ws;          // 14336 B (pad 16384)
    float* Qrot   = (float*)(ws + 16384);                        // 1 MiB
    u16*   Rpack  = (u16*)(ws + 16384 + 1048576);                // 2 MiB
    u16*   Qpack  = (u16*)(ws + 16384 + 1048576 + 2097152);      // 512 KiB

    hipMemsetAsync(best, 0, NU * BZn * sizeof(unsigned long long), stream);
    hipMemsetAsync(out, 0, sizeof(float), stream);

    k_qrot <<<64,  256, 0, stream>>>(query, R, Qrot);
    k_rpack<<<512, 256, 0, stream>>>(R, Rpack);
    k_qpack<<<128, 256, 0, stream>>>(Qrot, Qpack);

    hipFuncSetAttribute((const void*)k_main,
                        hipFuncAttributeMaxDynamicSharedMemorySize, LDS_TOT);
    k_main <<<MTOT / BM, 1024, LDS_TOT, stream>>>(keys, Rpack, Qpack, best);
    k_final<<<NU * BZn, 256, 0, stream>>>(keys, R, Qrot, best, out);
}